// Round 4
// baseline (251.009 us; speedup 1.0000x reference)
//
#include <hip/hip_runtime.h>
#include <hip/hip_bf16.h>

// CrissCrossAttention (actually full spatial attention with w<->k permuted PV):
//   B=4, C=512, H=W=64, C8=64, HW=4096.
// Pipeline (all bf16 MFMA 16x16x32, fp32 accum):
//   k_wcat : pack [wq;wk;wv] -> Wcat bf16 [640][512]
//   k_prep : x [B][512][4096] fp32 -> xT bf16 [B][4096][512]
//   k_proj : GEMM Wcat @ x  -> qfT/kfT bf16 [B][4096][64] (transposed), Vp bf16 [B][512][4096]
//   k_energy: e[hw][kv] = q.k (K=64), softmax over v (64-chunk local), -> P bf16 [hw][kv]
//   k_out  : out[c][(w,v)] = sum_{h,k} Vp[c][hk] * P[(h*64+w)][k*64+v]; gamma*out + x -> d_out

typedef __bf16 bf16_t;
typedef __bf16 bf16x8 __attribute__((ext_vector_type(8)));
typedef __bf16 bf16x4 __attribute__((ext_vector_type(4)));
typedef float f32x4 __attribute__((ext_vector_type(4)));

#define HW_ 4096
#define CIN 512
#define CQ 64
#define MTOT 640

__device__ __forceinline__ void gload16(const void* g, void* l) {
  __builtin_amdgcn_global_load_lds((const __attribute__((address_space(1))) void*)g,
                                   (__attribute__((address_space(3))) void*)l, 16, 0, 0);
}

// ---------------- weights pack ----------------
__global__ __launch_bounds__(256) void k_wcat(const float* __restrict__ wq,
                                              const float* __restrict__ wk,
                                              const float* __restrict__ wv,
                                              bf16_t* __restrict__ Wcat) {
  int idx = (blockIdx.x * 256 + threadIdx.x) * 4;  // grid sized exactly: 640*512/4 threads
  int row = idx >> 9, c = idx & 511;
  const float* src;
  if (row < 64)       src = wq + row * 512 + c;
  else if (row < 128) src = wk + (row - 64) * 512 + c;
  else                src = wv + (row - 128) * 512 + c;
  float4 v = *(const float4*)src;
  bf16x4 o = { (bf16_t)v.x, (bf16_t)v.y, (bf16_t)v.z, (bf16_t)v.w };
  *(bf16x4*)&Wcat[idx] = o;
}

// ---------------- x transpose + bf16 ----------------
__global__ __launch_bounds__(256) void k_prep(const float* __restrict__ x, bf16_t* __restrict__ xT) {
  __shared__ float tile[64][65];
  const int b = blockIdx.z;
  const int p0 = blockIdx.x * 64, c0 = blockIdx.y * 64;
  const float* xb = x + (size_t)b * CIN * HW_;
  bf16_t* xTb = xT + (size_t)b * HW_ * CIN;
  const int tid = threadIdx.x;
  const int r = tid >> 4, q = tid & 15;
#pragma unroll
  for (int i = 0; i < 4; ++i) {
    int lr = r + 16 * i;
    float4 v = *(const float4*)&xb[(size_t)(c0 + lr) * HW_ + p0 + q * 4];
    tile[lr][q * 4 + 0] = v.x; tile[lr][q * 4 + 1] = v.y;
    tile[lr][q * 4 + 2] = v.z; tile[lr][q * 4 + 3] = v.w;
  }
  __syncthreads();
#pragma unroll
  for (int i = 0; i < 4; ++i) {
    int pr = r + 16 * i;
    bf16x4 o;
    o[0] = (bf16_t)tile[q * 4 + 0][pr];
    o[1] = (bf16_t)tile[q * 4 + 1][pr];
    o[2] = (bf16_t)tile[q * 4 + 2][pr];
    o[3] = (bf16_t)tile[q * 4 + 3][pr];
    *(bf16x4*)&xTb[(size_t)(p0 + pr) * CIN + c0 + q * 4] = o;
  }
}

// ---------------- fused q/k/v projection GEMM ----------------
// D[m][n] = sum_c Wcat[m][c] * xT[n][c] + bias(m); m<64 -> qfT[n][m], m<128 -> kfT[n][m-64],
// else Vp[m-128][n].
__global__ __launch_bounds__(256) void k_proj(const bf16_t* __restrict__ Wcat,
                                              const bf16_t* __restrict__ xT,
                                              const float* __restrict__ bq,
                                              const float* __restrict__ bk,
                                              const float* __restrict__ bv,
                                              bf16_t* __restrict__ qfT,
                                              bf16_t* __restrict__ kfT,
                                              bf16_t* __restrict__ Vp) {
  __shared__ bf16_t As[128][64];
  __shared__ bf16_t Bs[128][64];
  const int b = blockIdx.z;
  const int m0 = blockIdx.x * 128, n0 = blockIdx.y * 128;
  const char* Wb = (const char*)Wcat;
  const char* Xb = (const char*)(xT + (size_t)b * HW_ * CIN);
  const int tid = threadIdx.x, wv_ = tid >> 6, lane = tid & 63;
  const int wm = wv_ >> 1, wn = wv_ & 1;
  f32x4 acc[4][4]{};
  for (int ks = 0; ks < 512; ks += 64) {
    if (ks) __syncthreads();
#pragma unroll
    for (int i = 0; i < 4; ++i) {
      int ch = wv_ * 4 + i;
      int rr = ch * 8 + (lane >> 3);
      gload16(Wb + (size_t)(m0 + rr) * 1024 + ks * 2 + (lane & 7) * 16, (char*)As + ch * 1024);
      gload16(Xb + (size_t)(n0 + rr) * 1024 + ks * 2 + (lane & 7) * 16, (char*)Bs + ch * 1024);
    }
    __syncthreads();
#pragma unroll
    for (int k2 = 0; k2 < 2; ++k2) {
      bf16x8 a[4], bb[4];
#pragma unroll
      for (int f = 0; f < 4; ++f)
        a[f] = *(const bf16x8*)&As[wm * 64 + f * 16 + (lane & 15)][k2 * 32 + (lane >> 4) * 8];
#pragma unroll
      for (int f = 0; f < 4; ++f)
        bb[f] = *(const bf16x8*)&Bs[wn * 64 + f * 16 + (lane & 15)][k2 * 32 + (lane >> 4) * 8];
#pragma unroll
      for (int fm = 0; fm < 4; ++fm)
#pragma unroll
        for (int fn = 0; fn < 4; ++fn)
          acc[fm][fn] = __builtin_amdgcn_mfma_f32_16x16x32_bf16(a[fm], bb[fn], acc[fm][fn], 0, 0, 0);
    }
  }
  bf16_t* qb = qfT + (size_t)b * HW_ * CQ;
  bf16_t* kb = kfT + (size_t)b * HW_ * CQ;
  bf16_t* Vb = Vp + (size_t)b * CIN * HW_;
#pragma unroll
  for (int fm = 0; fm < 4; ++fm) {
#pragma unroll
    for (int j = 0; j < 4; ++j) {
      int m = m0 + wm * 64 + fm * 16 + (lane >> 4) * 4 + j;
      float bias = (m < 64) ? bq[m] : (m < 128) ? bk[m - 64] : bv[m - 128];
#pragma unroll
      for (int fn = 0; fn < 4; ++fn) {
        int n = n0 + wn * 64 + fn * 16 + (lane & 15);
        float val = acc[fm][fn][j] + bias;
        if (m < 64)       qb[(size_t)n * CQ + m] = (bf16_t)val;
        else if (m < 128) kb[(size_t)n * CQ + (m - 64)] = (bf16_t)val;
        else              Vb[(size_t)(m - 128) * HW_ + n] = (bf16_t)val;
      }
    }
  }
}

// ---------------- energy + softmax(v) -> P ----------------
// e[hw][kv] = sum_c qfT[hw][c]*kfT[kv][c]; softmax over v (kv%64) local to the 64-wide tile.
__global__ __launch_bounds__(256) void k_energy(const bf16_t* __restrict__ qfT,
                                                const bf16_t* __restrict__ kfT,
                                                bf16_t* __restrict__ P4, int zbase) {
  __shared__ bf16_t As[128][64];
  __shared__ bf16_t Bs[64][64];
  const int b = zbase + blockIdx.z;
  const int m0 = blockIdx.x * 128, n0 = blockIdx.y * 64;
  const char* qb = (const char*)(qfT + (size_t)b * HW_ * CQ);
  const char* kb = (const char*)(kfT + (size_t)b * HW_ * CQ);
  bf16_t* Pb = P4 + (size_t)blockIdx.z * (size_t)HW_ * HW_;
  const int tid = threadIdx.x, wv_ = tid >> 6, lane = tid & 63;
  f32x4 acc[2][4]{};
#pragma unroll
  for (int i = 0; i < 4; ++i) {
    int ch = wv_ * 4 + i;
    gload16(qb + (size_t)m0 * 128 + ch * 1024 + lane * 16, (char*)As + ch * 1024);
  }
#pragma unroll
  for (int i = 0; i < 2; ++i) {
    int ch = wv_ * 2 + i;
    gload16(kb + (size_t)n0 * 128 + ch * 1024 + lane * 16, (char*)Bs + ch * 1024);
  }
  __syncthreads();
#pragma unroll
  for (int k2 = 0; k2 < 2; ++k2) {
    bf16x8 a[2], bb[4];
#pragma unroll
    for (int f = 0; f < 2; ++f)
      a[f] = *(const bf16x8*)&As[wv_ * 32 + f * 16 + (lane & 15)][k2 * 32 + (lane >> 4) * 8];
#pragma unroll
    for (int f = 0; f < 4; ++f)
      bb[f] = *(const bf16x8*)&Bs[f * 16 + (lane & 15)][k2 * 32 + (lane >> 4) * 8];
#pragma unroll
    for (int fm = 0; fm < 2; ++fm)
#pragma unroll
      for (int fn = 0; fn < 4; ++fn)
        acc[fm][fn] = __builtin_amdgcn_mfma_f32_16x16x32_bf16(a[fm], bb[fn], acc[fm][fn], 0, 0, 0);
  }
#pragma unroll
  for (int fm = 0; fm < 2; ++fm) {
#pragma unroll
    for (int j = 0; j < 4; ++j) {
      float mx = fmaxf(fmaxf(acc[fm][0][j], acc[fm][1][j]), fmaxf(acc[fm][2][j], acc[fm][3][j]));
#pragma unroll
      for (int d = 1; d < 16; d <<= 1) mx = fmaxf(mx, __shfl_xor(mx, d, 64));
      float p0 = __expf(acc[fm][0][j] - mx);
      float p1 = __expf(acc[fm][1][j] - mx);
      float p2 = __expf(acc[fm][2][j] - mx);
      float p3 = __expf(acc[fm][3][j] - mx);
      float s = p0 + p1 + p2 + p3;
#pragma unroll
      for (int d = 1; d < 16; d <<= 1) s += __shfl_xor(s, d, 64);
      float inv = __builtin_amdgcn_rcpf(s);  // s >= 1 always (max-subtracted)
      size_t hw = (size_t)(m0 + wv_ * 32 + fm * 16 + (lane >> 4) * 4 + j);
      size_t base = hw * HW_ + n0 + (lane & 15);
      Pb[base + 0]  = (bf16_t)(p0 * inv);
      Pb[base + 16] = (bf16_t)(p1 * inv);
      Pb[base + 32] = (bf16_t)(p2 * inv);
      Pb[base + 48] = (bf16_t)(p3 * inv);
    }
  }
}

// ---------------- out GEMM + epilogue ----------------
// N-tile = (w fixed, v 0..63); K-step h: B-tile = P[(h*64+w)*4096 + k*64+v] contiguous 8KB.
__global__ __launch_bounds__(256) void k_out(const bf16_t* __restrict__ Vp,
                                             const bf16_t* __restrict__ P4,
                                             const float* __restrict__ x,
                                             const float* __restrict__ gamma,
                                             float* __restrict__ outp, int zbase) {
  __shared__ bf16_t As[128][64];
  __shared__ bf16_t Bs[64][64];
  const int b = zbase + blockIdx.z;
  const int c0 = blockIdx.x * 128, w = blockIdx.y;
  const char* Vb = (const char*)(Vp + (size_t)b * CIN * HW_);
  const char* Pb = (const char*)(P4 + (size_t)blockIdx.z * (size_t)HW_ * HW_);
  const int tid = threadIdx.x, wv_ = tid >> 6, lane = tid & 63;
  const int wm = wv_ >> 1, wn = wv_ & 1;
  f32x4 acc[4][2]{};
  for (int h = 0; h < 64; ++h) {
#pragma unroll
    for (int i = 0; i < 4; ++i) {
      int ch = wv_ * 4 + i;
      int rr = ch * 8 + (lane >> 3);
      gload16(Vb + (size_t)(c0 + rr) * 8192 + h * 128 + (lane & 7) * 16, (char*)As + ch * 1024);
    }
#pragma unroll
    for (int i = 0; i < 2; ++i) {
      int ch = wv_ * 2 + i;
      gload16(Pb + (size_t)(h * 64 + w) * 8192 + ch * 1024 + lane * 16, (char*)Bs + ch * 1024);
    }
    __syncthreads();
#pragma unroll
    for (int k2 = 0; k2 < 2; ++k2) {
      bf16x8 a[4];
#pragma unroll
      for (int f = 0; f < 4; ++f)
        a[f] = *(const bf16x8*)&As[wm * 64 + f * 16 + (lane & 15)][k2 * 32 + (lane >> 4) * 8];
#pragma unroll
      for (int fn = 0; fn < 2; ++fn) {
        int v = wn * 32 + fn * 16 + (lane & 15);
        int kk = k2 * 32 + (lane >> 4) * 8;
        bf16x8 bb;
#pragma unroll
        for (int j = 0; j < 8; ++j) bb[j] = Bs[kk + j][v];
#pragma unroll
        for (int fm = 0; fm < 4; ++fm)
          acc[fm][fn] = __builtin_amdgcn_mfma_f32_16x16x32_bf16(a[fm], bb, acc[fm][fn], 0, 0, 0);
      }
    }
    __syncthreads();
  }
  const float g = gamma[0];
  const float* xb = x + (size_t)b * CIN * HW_;
  float* ob = outp + (size_t)b * CIN * HW_;
#pragma unroll
  for (int fm = 0; fm < 4; ++fm) {
#pragma unroll
    for (int j = 0; j < 4; ++j) {
      int c = c0 + wm * 64 + fm * 16 + (lane >> 4) * 4 + j;
#pragma unroll
      for (int fn = 0; fn < 2; ++fn) {
        int n = w * 64 + wn * 32 + fn * 16 + (lane & 15);
        size_t idx = (size_t)c * HW_ + n;
        ob[idx] = g * acc[fm][fn][j] + xb[idx];
      }
    }
  }
}

extern "C" void kernel_launch(void* const* d_in, const int* in_sizes, int n_in,
                              void* d_out, int out_size, void* d_ws, size_t ws_size,
                              hipStream_t stream) {
  const float* x  = (const float*)d_in[0];
  const float* wq = (const float*)d_in[1];
  const float* bq = (const float*)d_in[2];
  const float* wk = (const float*)d_in[3];
  const float* bk = (const float*)d_in[4];
  const float* wv = (const float*)d_in[5];
  const float* bv = (const float*)d_in[6];
  const float* gamma = (const float*)d_in[7];
  float* outp = (float*)d_out;
  char* ws = (char*)d_ws;
  size_t off = 0;
  bf16_t* xT   = (bf16_t*)(ws + off); off += (size_t)4 * HW_ * CIN * 2;   // 16 MB
  bf16_t* Wcat = (bf16_t*)(ws + off); off += (size_t)MTOT * CIN * 2;      // 640 KB
  bf16_t* qfT  = (bf16_t*)(ws + off); off += (size_t)4 * HW_ * CQ * 2;    // 2 MB
  bf16_t* kfT  = (bf16_t*)(ws + off); off += (size_t)4 * HW_ * CQ * 2;    // 2 MB
  bf16_t* Vp   = (bf16_t*)(ws + off); off += (size_t)4 * CIN * HW_ * 2;   // 16 MB
  bf16_t* P4   = (bf16_t*)(ws + off);
  const size_t pbytes = (size_t)HW_ * HW_ * 2;                            // 32 MB / batch
  const bool full = (ws_size >= off + 4 * pbytes);

  k_wcat<<<dim3(320), dim3(256), 0, stream>>>(wq, wk, wv, Wcat);
  k_prep<<<dim3(64, 8, 4), dim3(256), 0, stream>>>(x, xT);
  k_proj<<<dim3(5, 32, 4), dim3(256), 0, stream>>>(Wcat, xT, bq, bk, bv, qfT, kfT, Vp);
  if (full) {
    k_energy<<<dim3(32, 64, 4), dim3(256), 0, stream>>>(qfT, kfT, P4, 0);
    k_out<<<dim3(4, 64, 4), dim3(256), 0, stream>>>(Vp, P4, x, gamma, outp, 0);
  } else {
    for (int b = 0; b < 4; ++b) {
      k_energy<<<dim3(32, 64, 1), dim3(256), 0, stream>>>(qfT, kfT, P4, b);
      k_out<<<dim3(4, 64, 1), dim3(256), 0, stream>>>(Vp, P4, x, gamma, outp, b);
    }
  }
}

// Round 6
// 184.232 us; speedup vs baseline: 1.3625x; 1.3625x over previous
//
#include <hip/hip_runtime.h>
#include <hip/hip_bf16.h>

// CrissCrossAttention (full spatial attention with w<->k permuted PV):
//   B=4, C=512, H=W=64, C8=64, HW=4096.
// Pipeline (all bf16 MFMA 16x16x32, fp32 accum):
//   k_wcat : pack [wq;wk;wv] -> Wcat bf16 [640][512]
//   k_prep : x [B][512][4096] fp32 -> xT bf16 [B][4096][512]
//   k_proj : GEMM Wcat @ x  -> qfT/kfT bf16 [B][4096][64] (transposed), Vp bf16 [B][512][4096]
//   k_energy: e[hw][kv] = q.k (K=64), softmax over v (64-chunk local), -> P bf16 [hw][kv]
//   k_out  : out[c][(w,v)] = sum_{h,k} Vp[c][hk] * P[(h*64+w)][k*64+v]; gamma*out + x.
//     v3: block 128c x (2w x 64v), 4 waves (2x2), wave tile 64x64.
//         A (Vp): LDS [128][8 slot16B], slot ^= row&7, swizzle pre-applied on the
//           global source (linear gload_lds dest) -> bank-optimal ds_read_b128.
//         B (P): LDS [2w][64k][64v] natural rows, v_lds = v ^ ((k>>3)&3)<<4 chunk
//           swizzle on source -> conflict-free scalar u16 gather, loop-invariant addrs.
//         No inline asm; compiler-managed waitcnts.

typedef __bf16 bf16_t;
typedef __bf16 bf16x8 __attribute__((ext_vector_type(8)));
typedef __bf16 bf16x4 __attribute__((ext_vector_type(4)));
typedef float f32x4 __attribute__((ext_vector_type(4)));

#define HW_ 4096
#define CIN 512
#define CQ 64
#define MTOT 640

__device__ __forceinline__ void gload16(const void* g, void* l) {
  __builtin_amdgcn_global_load_lds((const __attribute__((address_space(1))) void*)g,
                                   (__attribute__((address_space(3))) void*)l, 16, 0, 0);
}

// ---------------- weights pack ----------------
__global__ __launch_bounds__(256) void k_wcat(const float* __restrict__ wq,
                                              const float* __restrict__ wk,
                                              const float* __restrict__ wv,
                                              bf16_t* __restrict__ Wcat) {
  int idx = (blockIdx.x * 256 + threadIdx.x) * 4;
  int row = idx >> 9, c = idx & 511;
  const float* src;
  if (row < 64)       src = wq + row * 512 + c;
  else if (row < 128) src = wk + (row - 64) * 512 + c;
  else                src = wv + (row - 128) * 512 + c;
  float4 v = *(const float4*)src;
  bf16x4 o = { (bf16_t)v.x, (bf16_t)v.y, (bf16_t)v.z, (bf16_t)v.w };
  *(bf16x4*)&Wcat[idx] = o;
}

// ---------------- x transpose + bf16 ----------------
__global__ __launch_bounds__(256) void k_prep(const float* __restrict__ x, bf16_t* __restrict__ xT) {
  __shared__ float tile[64][65];
  const int b = blockIdx.z;
  const int p0 = blockIdx.x * 64, c0 = blockIdx.y * 64;
  const float* xb = x + (size_t)b * CIN * HW_;
  bf16_t* xTb = xT + (size_t)b * HW_ * CIN;
  const int tid = threadIdx.x;
  const int r = tid >> 4, q = tid & 15;
#pragma unroll
  for (int i = 0; i < 4; ++i) {
    int lr = r + 16 * i;
    float4 v = *(const float4*)&xb[(size_t)(c0 + lr) * HW_ + p0 + q * 4];
    tile[lr][q * 4 + 0] = v.x; tile[lr][q * 4 + 1] = v.y;
    tile[lr][q * 4 + 2] = v.z; tile[lr][q * 4 + 3] = v.w;
  }
  __syncthreads();
#pragma unroll
  for (int i = 0; i < 4; ++i) {
    int pr = r + 16 * i;
    bf16x4 o;
    o[0] = (bf16_t)tile[q * 4 + 0][pr];
    o[1] = (bf16_t)tile[q * 4 + 1][pr];
    o[2] = (bf16_t)tile[q * 4 + 2][pr];
    o[3] = (bf16_t)tile[q * 4 + 3][pr];
    *(bf16x4*)&xTb[(size_t)(p0 + pr) * CIN + c0 + q * 4] = o;
  }
}

// ---------------- fused q/k/v projection GEMM ----------------
__global__ __launch_bounds__(256) void k_proj(const bf16_t* __restrict__ Wcat,
                                              const bf16_t* __restrict__ xT,
                                              const float* __restrict__ bq,
                                              const float* __restrict__ bk,
                                              const float* __restrict__ bv,
                                              bf16_t* __restrict__ qfT,
                                              bf16_t* __restrict__ kfT,
                                              bf16_t* __restrict__ Vp) {
  __shared__ bf16_t As[128][64];
  __shared__ bf16_t Bs[128][64];
  const int b = blockIdx.z;
  const int m0 = blockIdx.x * 128, n0 = blockIdx.y * 128;
  const char* Wb = (const char*)Wcat;
  const char* Xb = (const char*)(xT + (size_t)b * HW_ * CIN);
  const int tid = threadIdx.x, wv_ = tid >> 6, lane = tid & 63;
  const int wm = wv_ >> 1, wn = wv_ & 1;
  f32x4 acc[4][4]{};
  for (int ks = 0; ks < 512; ks += 64) {
    if (ks) __syncthreads();
#pragma unroll
    for (int i = 0; i < 4; ++i) {
      int ch = wv_ * 4 + i;
      int rr = ch * 8 + (lane >> 3);
      gload16(Wb + (size_t)(m0 + rr) * 1024 + ks * 2 + (lane & 7) * 16, (char*)As + ch * 1024);
      gload16(Xb + (size_t)(n0 + rr) * 1024 + ks * 2 + (lane & 7) * 16, (char*)Bs + ch * 1024);
    }
    __syncthreads();
#pragma unroll
    for (int k2 = 0; k2 < 2; ++k2) {
      bf16x8 a[4], bb[4];
#pragma unroll
      for (int f = 0; f < 4; ++f)
        a[f] = *(const bf16x8*)&As[wm * 64 + f * 16 + (lane & 15)][k2 * 32 + (lane >> 4) * 8];
#pragma unroll
      for (int f = 0; f < 4; ++f)
        bb[f] = *(const bf16x8*)&Bs[wn * 64 + f * 16 + (lane & 15)][k2 * 32 + (lane >> 4) * 8];
#pragma unroll
      for (int fm = 0; fm < 4; ++fm)
#pragma unroll
        for (int fn = 0; fn < 4; ++fn)
          acc[fm][fn] = __builtin_amdgcn_mfma_f32_16x16x32_bf16(a[fm], bb[fn], acc[fm][fn], 0, 0, 0);
    }
  }
  bf16_t* qb = qfT + (size_t)b * HW_ * CQ;
  bf16_t* kb = kfT + (size_t)b * HW_ * CQ;
  bf16_t* Vb = Vp + (size_t)b * CIN * HW_;
#pragma unroll
  for (int fm = 0; fm < 4; ++fm) {
#pragma unroll
    for (int j = 0; j < 4; ++j) {
      int m = m0 + wm * 64 + fm * 16 + (lane >> 4) * 4 + j;
      float bias = (m < 64) ? bq[m] : (m < 128) ? bk[m - 64] : bv[m - 128];
#pragma unroll
      for (int fn = 0; fn < 4; ++fn) {
        int n = n0 + wn * 64 + fn * 16 + (lane & 15);
        float val = acc[fm][fn][j] + bias;
        if (m < 64)       qb[(size_t)n * CQ + m] = (bf16_t)val;
        else if (m < 128) kb[(size_t)n * CQ + (m - 64)] = (bf16_t)val;
        else              Vb[(size_t)(m - 128) * HW_ + n] = (bf16_t)val;
      }
    }
  }
}

// ---------------- energy + softmax(v) -> P ----------------
__global__ __launch_bounds__(256) void k_energy(const bf16_t* __restrict__ qfT,
                                                const bf16_t* __restrict__ kfT,
                                                bf16_t* __restrict__ P4, int zbase) {
  __shared__ bf16_t As[128][64];
  __shared__ bf16_t Bs[64][64];
  const int b = zbase + blockIdx.z;
  const int m0 = blockIdx.x * 128, n0 = blockIdx.y * 64;
  const char* qb = (const char*)(qfT + (size_t)b * HW_ * CQ);
  const char* kb = (const char*)(kfT + (size_t)b * HW_ * CQ);
  bf16_t* Pb = P4 + (size_t)blockIdx.z * (size_t)HW_ * HW_;
  const int tid = threadIdx.x, wv_ = tid >> 6, lane = tid & 63;
  f32x4 acc[2][4]{};
#pragma unroll
  for (int i = 0; i < 4; ++i) {
    int ch = wv_ * 4 + i;
    gload16(qb + (size_t)m0 * 128 + ch * 1024 + lane * 16, (char*)As + ch * 1024);
  }
#pragma unroll
  for (int i = 0; i < 2; ++i) {
    int ch = wv_ * 2 + i;
    gload16(kb + (size_t)n0 * 128 + ch * 1024 + lane * 16, (char*)Bs + ch * 1024);
  }
  __syncthreads();
#pragma unroll
  for (int k2 = 0; k2 < 2; ++k2) {
    bf16x8 a[2], bb[4];
#pragma unroll
    for (int f = 0; f < 2; ++f)
      a[f] = *(const bf16x8*)&As[wv_ * 32 + f * 16 + (lane & 15)][k2 * 32 + (lane >> 4) * 8];
#pragma unroll
    for (int f = 0; f < 4; ++f)
      bb[f] = *(const bf16x8*)&Bs[f * 16 + (lane & 15)][k2 * 32 + (lane >> 4) * 8];
#pragma unroll
    for (int fm = 0; fm < 2; ++fm)
#pragma unroll
      for (int fn = 0; fn < 4; ++fn)
        acc[fm][fn] = __builtin_amdgcn_mfma_f32_16x16x32_bf16(a[fm], bb[fn], acc[fm][fn], 0, 0, 0);
  }
#pragma unroll
  for (int fm = 0; fm < 2; ++fm) {
#pragma unroll
    for (int j = 0; j < 4; ++j) {
      float mx = fmaxf(fmaxf(acc[fm][0][j], acc[fm][1][j]), fmaxf(acc[fm][2][j], acc[fm][3][j]));
#pragma unroll
      for (int d = 1; d < 16; d <<= 1) mx = fmaxf(mx, __shfl_xor(mx, d, 64));
      float p0 = __expf(acc[fm][0][j] - mx);
      float p1 = __expf(acc[fm][1][j] - mx);
      float p2 = __expf(acc[fm][2][j] - mx);
      float p3 = __expf(acc[fm][3][j] - mx);
      float s = p0 + p1 + p2 + p3;
#pragma unroll
      for (int d = 1; d < 16; d <<= 1) s += __shfl_xor(s, d, 64);
      float inv = __builtin_amdgcn_rcpf(s);
      size_t hw = (size_t)(m0 + wv_ * 32 + fm * 16 + (lane >> 4) * 4 + j);
      size_t base = hw * HW_ + n0 + (lane & 15);
      Pb[base + 0]  = (bf16_t)(p0 * inv);
      Pb[base + 16] = (bf16_t)(p1 * inv);
      Pb[base + 32] = (bf16_t)(p2 * inv);
      Pb[base + 48] = (bf16_t)(p3 * inv);
    }
  }
}

// ---------------- out GEMM v3 + epilogue ----------------
__global__ __launch_bounds__(256) void k_out(const bf16_t* __restrict__ Vp,
                                             const bf16_t* __restrict__ P4,
                                             const float* __restrict__ x,
                                             const float* __restrict__ gamma,
                                             float* __restrict__ outp, int zbase) {
  __shared__ char As[16384];   // A: [128 rows][8 slots of 16B], slot ^= row&7
  __shared__ char Bs[16384];   // B: [2 w][64 k][64 v], v ^= ((k>>3)&3)<<4
  const int b = zbase + blockIdx.z;
  const int c0 = blockIdx.x * 128, w0 = blockIdx.y * 2;
  const char* Vb = (const char*)(Vp + (size_t)b * CIN * HW_);
  const char* Pb = (const char*)(P4 + (size_t)blockIdx.z * (size_t)HW_ * HW_);
  const int tid = threadIdx.x, wv_ = tid >> 6, lane = tid & 63;
  const int wm = wv_ >> 1, wn = wv_ & 1;
  const int g = lane >> 4, cc = lane & 15;

  // Staging sources (h=0), swizzles pre-applied on the global side; LDS dest linear.
  const char* aS[4]; const char* bS[4]; char* aD[4]; char* bD[4];
#pragma unroll
  for (int r = 0; r < 4; ++r) {
    int L = (r * 4 + wv_) * 64 + lane;              // 16B-chunk index 0..1023
    int arow = L >> 3, aslot = (L & 7) ^ (arow & 7);
    aS[r] = Vb + (size_t)(c0 + arow) * 8192 + aslot * 16;
    int ws = L >> 9, e = L & 511;
    int kk = e >> 3, sl = (e & 7) ^ ((kk >> 3) & 3) << 1;
    bS[r] = Pb + (size_t)(w0 + ws) * 8192 + kk * 128 + sl * 16;
    aD[r] = As + (r * 4 + wv_) * 1024;
    bD[r] = Bs + (r * 4 + wv_) * 1024;
  }
  // Loop-invariant LDS read offsets.
  int aoff[2][4], boff[2][4];
#pragma unroll
  for (int k2 = 0; k2 < 2; ++k2) {
#pragma unroll
    for (int fm = 0; fm < 4; ++fm)
      aoff[k2][fm] = (wm * 64 + fm * 16 + cc) * 128 + (((k2 * 4 + g) ^ (cc & 7)) * 16);
#pragma unroll
    for (int fn = 0; fn < 4; ++fn)
      boff[k2][fn] = wn * 8192 + (k2 * 32 + g * 8) * 128 + (((fn * 16 + cc) ^ (g << 4)) * 2);
  }

  f32x4 acc[4][4]{};
  for (int h = 0; h < 64; ++h) {
#pragma unroll
    for (int r = 0; r < 4; ++r) gload16(aS[r], aD[r]);
#pragma unroll
    for (int r = 0; r < 4; ++r) gload16(bS[r], bD[r]);
#pragma unroll
    for (int r = 0; r < 4; ++r) { aS[r] += 128; bS[r] += 524288; }
    __syncthreads();
#pragma unroll
    for (int k2 = 0; k2 < 2; ++k2) {
      bf16x8 a[4], bb[4];
#pragma unroll
      for (int fm = 0; fm < 4; ++fm)
        a[fm] = *(const bf16x8*)(As + aoff[k2][fm]);
#pragma unroll
      for (int fn = 0; fn < 4; ++fn) {
#pragma unroll
        for (int j = 0; j < 8; ++j)
          bb[fn][j] = *(const bf16_t*)(Bs + boff[k2][fn] + j * 128);
      }
#pragma unroll
      for (int fm = 0; fm < 4; ++fm)
#pragma unroll
        for (int fn = 0; fn < 4; ++fn)
          acc[fm][fn] = __builtin_amdgcn_mfma_f32_16x16x32_bf16(a[fm], bb[fn], acc[fm][fn], 0, 0, 0);
    }
    __syncthreads();
  }
  const float gmm = gamma[0];
  const float* xb = x + (size_t)b * CIN * HW_;
  float* ob = outp + (size_t)b * CIN * HW_;
  const int w = w0 + wn;
#pragma unroll
  for (int fm = 0; fm < 4; ++fm) {
#pragma unroll
    for (int jj = 0; jj < 4; ++jj) {
      int c = c0 + wm * 64 + fm * 16 + g * 4 + jj;
#pragma unroll
      for (int fn = 0; fn < 4; ++fn) {
        int n = w * 64 + fn * 16 + cc;
        size_t idx = (size_t)c * HW_ + n;
        ob[idx] = gmm * acc[fm][fn][jj] + xb[idx];
      }
    }
  }
}

extern "C" void kernel_launch(void* const* d_in, const int* in_sizes, int n_in,
                              void* d_out, int out_size, void* d_ws, size_t ws_size,
                              hipStream_t stream) {
  const float* x  = (const float*)d_in[0];
  const float* wq = (const float*)d_in[1];
  const float* bq = (const float*)d_in[2];
  const float* wk = (const float*)d_in[3];
  const float* bk = (const float*)d_in[4];
  const float* wv = (const float*)d_in[5];
  const float* bv = (const float*)d_in[6];
  const float* gamma = (const float*)d_in[7];
  float* outp = (float*)d_out;
  char* ws = (char*)d_ws;
  size_t off = 0;
  bf16_t* xT   = (bf16_t*)(ws + off); off += (size_t)4 * HW_ * CIN * 2;   // 16 MB
  bf16_t* Wcat = (bf16_t*)(ws + off); off += (size_t)MTOT * CIN * 2;      // 640 KB
  bf16_t* qfT  = (bf16_t*)(ws + off); off += (size_t)4 * HW_ * CQ * 2;    // 2 MB
  bf16_t* kfT  = (bf16_t*)(ws + off); off += (size_t)4 * HW_ * CQ * 2;    // 2 MB
  bf16_t* Vp   = (bf16_t*)(ws + off); off += (size_t)4 * CIN * HW_ * 2;   // 16 MB
  bf16_t* P4   = (bf16_t*)(ws + off);
  const size_t pbytes = (size_t)HW_ * HW_ * 2;                            // 32 MB / batch
  const bool full = (ws_size >= off + 4 * pbytes);

  k_wcat<<<dim3(320), dim3(256), 0, stream>>>(wq, wk, wv, Wcat);
  k_prep<<<dim3(64, 8, 4), dim3(256), 0, stream>>>(x, xT);
  k_proj<<<dim3(5, 32, 4), dim3(256), 0, stream>>>(Wcat, xT, bq, bk, bv, qfT, kfT, Vp);
  if (full) {
    k_energy<<<dim3(32, 64, 4), dim3(256), 0, stream>>>(qfT, kfT, P4, 0);
    k_out<<<dim3(4, 32, 4), dim3(256), 0, stream>>>(Vp, P4, x, gamma, outp, 0);
  } else {
    for (int b = 0; b < 4; ++b) {
      k_energy<<<dim3(32, 64, 1), dim3(256), 0, stream>>>(qfT, kfT, P4, b);
      k_out<<<dim3(4, 32, 1), dim3(256), 0, stream>>>(Vp, P4, x, gamma, outp, b);
    }
  }
}